// Round 11
// baseline (643.887 us; speedup 1.0000x reference)
//
#include <hip/hip_runtime.h>
#include <hip/hip_bf16.h>
#include <math.h>

#define N_ENT   40000
#define N_REL2  480
#define D       128
#define T_STEPS 8
#define E_EDGES 200000
#define SQC     0.1f                 // sqrt(C), C = 0.01
#define RRELU_SLOPE 0.22916666666666666f
#define EPS_    1e-6f
#define NPAD    40960                // 40 blocks x 1024 (scan padding)

typedef _Float16 f16;
typedef _Float16 f16x8 __attribute__((ext_vector_type(8)));
typedef _Float16 f16x4 __attribute__((ext_vector_type(4)));
typedef _Float16 f16x2 __attribute__((ext_vector_type(2)));
typedef float    f32x4 __attribute__((ext_vector_type(4)));

// ---------------------------------------------------------------------------
// emb_rel16 = (f16) emb_rel
// ---------------------------------------------------------------------------
__global__ __launch_bounds__(256) void cvt_rel_kernel(const float* __restrict__ emb_rel,
                                                      f16* __restrict__ emb_rel16) {
    int i = blockIdx.x * blockDim.x + threadIdx.x;
    if (i < N_REL2 * D) emb_rel16[i] = (f16)emb_rel[i];
}

// ---------------------------------------------------------------------------
// Wpack: fragment-layout fp16 pack of {wn,wl,wg}.
// ---------------------------------------------------------------------------
__global__ __launch_bounds__(256) void cvtw_kernel(const float* __restrict__ wn,
                                                   const float* __restrict__ wl,
                                                   const float* __restrict__ wg,
                                                   f16* __restrict__ wpack) {
    int idx = blockIdx.x * blockDim.x + threadIdx.x;   // 0 .. 49151
    int j    = idx & 7;
    int lane = (idx >> 3) & 63;
    int ks   = (idx >> 9) & 3;
    int nt   = (idx >> 11) & 7;
    int g    = idx >> 14;
    const float* W = (g == 0) ? wn : (g == 1) ? wl : wg;
    int k = ks * 32 + (lane >> 4) * 8 + j;
    int n = nt * 16 + (lane & 15);
    wpack[idx] = (f16)W[k * D + n];
}

// ---------------------------------------------------------------------------
// logmap0 of initial h: h_tan (fp32) + h_tan16 (fp16)
// ---------------------------------------------------------------------------
__global__ __launch_bounds__(256) void logmap_kernel(const float* __restrict__ h,
                                                     float* __restrict__ h_tan,
                                                     f16* __restrict__ h_tan16) {
    int wid  = (blockIdx.x * blockDim.x + threadIdx.x) >> 6;
    int lane = threadIdx.x & 63;
    if (wid >= N_ENT) return;
    int base = wid * D + lane * 2;
    float2 hv = *reinterpret_cast<const float2*>(h + base);
    float ss = hv.x * hv.x + hv.y * hv.y;
    #pragma unroll
    for (int off = 32; off >= 1; off >>= 1) ss += __shfl_xor(ss, off, 64);
    float n = fmaxf(sqrtf(ss), EPS_);
    float t = fminf(SQC * n, 1.0f - 1e-5f);
    float scale = atanhf(t) / (SQC * n);
    float ox = hv.x * scale, oy = hv.y * scale;
    *reinterpret_cast<float2*>(h_tan + base) = make_float2(ox, oy);
    f16x2 o16 = {(f16)ox, (f16)oy};
    *reinterpret_cast<f16x2*>(h_tan16 + base) = o16;
}

// ---------------------------------------------------------------------------
// CSR build (counting sort by dst), int atomics only
// ---------------------------------------------------------------------------
__global__ __launch_bounds__(256) void hist_kernel(const int* __restrict__ dst,
                                                   int* __restrict__ hist) {
    int t = blockIdx.y;
    int e = blockIdx.x * blockDim.x + threadIdx.x;
    if (e >= E_EDGES) return;
    atomicAdd(&hist[t * N_ENT + dst[(size_t)t * E_EDGES + e]], 1);
}

__global__ __launch_bounds__(1024) void scanA_kernel(const int* __restrict__ hist,
                                                     int* __restrict__ scanned,
                                                     int* __restrict__ partial) {
    __shared__ int s[1024];
    int t = blockIdx.y, blk = blockIdx.x, tid = threadIdx.x;
    int idx = blk * 1024 + tid;
    int v = (idx < N_ENT) ? hist[t * N_ENT + idx] : 0;
    s[tid] = v; __syncthreads();
    #pragma unroll
    for (int off = 1; off < 1024; off <<= 1) {
        int x = (tid >= off) ? s[tid - off] : 0;
        __syncthreads();
        s[tid] += x;
        __syncthreads();
    }
    scanned[t * NPAD + idx] = s[tid];
    if (tid == 1023) partial[t * 40 + blk] = s[1023];
}

__global__ __launch_bounds__(64) void scanB_kernel(int* __restrict__ partial) {
    int t = blockIdx.x, tid = threadIdx.x;
    int orig = (tid < 40) ? partial[t * 40 + tid] : 0;
    int v = orig;
    #pragma unroll
    for (int off = 1; off < 64; off <<= 1) {
        int x = __shfl_up(v, off, 64);
        if (tid >= off) v += x;
    }
    if (tid < 40) partial[t * 40 + tid] = v - orig;   // exclusive
}

__global__ __launch_bounds__(1024) void scanC_kernel(const int* __restrict__ hist,
                                                     const int* __restrict__ scanned,
                                                     const int* __restrict__ partial,
                                                     int* __restrict__ row_ptr,
                                                     int* __restrict__ cursor) {
    int t = blockIdx.y, blk = blockIdx.x, tid = threadIdx.x;
    int idx = blk * 1024 + tid;
    if (idx >= N_ENT) return;
    int incl = scanned[t * NPAD + idx] + partial[t * 40 + blk];
    row_ptr[t * (N_ENT + 1) + idx + 1] = incl;
    cursor[t * N_ENT + idx] = incl - hist[t * N_ENT + idx];
    if (idx == 0) row_ptr[t * (N_ENT + 1)] = 0;
}

// pack (src, rel) into one 32-bit word: src < 2^16, rel < 2^9
__global__ __launch_bounds__(256) void scatter_kernel(const int* __restrict__ src,
                                                      const int* __restrict__ dst,
                                                      const int* __restrict__ rel,
                                                      int* __restrict__ cursor,
                                                      unsigned* __restrict__ sorted) {
    int t = blockIdx.y;
    int e = blockIdx.x * blockDim.x + threadIdx.x;
    if (e >= E_EDGES) return;
    size_t o = (size_t)t * E_EDGES + e;
    int d = dst[o];
    int pos = atomicAdd(&cursor[t * N_ENT + d], 1);
    sorted[(size_t)t * E_EDGES + pos] = (unsigned)src[o] | ((unsigned)rel[o] << 16);
}

// ---------------------------------------------------------------------------
// FUSED STEP (double-buffered fp16 state: read h16_cur, write h16_nxt —
// cross-block gather reads make in-place update a race, R10 lesson):
//   phase 1: stage h16_cur tile into a_s (swizzled)
//   phase 2: wave w gathers nodes w*16..w*16+15: M[n] = mean(h16_cur[s]+er[r])
//   phase 3: P=M@wn, L=ht@wl, G=ht@wg via MFMA; mix epilogue;
//            !last: write h_tan/h16_nxt; last: h_out = expmap0(mixed)
// ---------------------------------------------------------------------------
__global__ __launch_bounds__(256) void fused_step_kernel(
        const f16* __restrict__ h16_cur, f16* __restrict__ h16_nxt,
        float* __restrict__ h_tan,
        const f16* __restrict__ emb_rel16, const f16* __restrict__ wpack,
        const int* __restrict__ row_ptr, const unsigned* __restrict__ sorted,
        float* __restrict__ h_out, int last) {
    __shared__ f16 m_s[64 * 128];
    __shared__ f16 a_s[64 * 128];
    const int tid = threadIdx.x;
    const int rowBase = blockIdx.x * 64;
    const int wave = tid >> 6, lane = tid & 63;

    // --- phase 1: stage h16_cur tile (all 256 threads), XOR-swizzled
    {
        int r = tid >> 2, q = tid & 3;
        const float4* srcA = reinterpret_cast<const float4*>(h16_cur + (size_t)(rowBase + r) * D + q * 32);
        #pragma unroll
        for (int i = 0; i < 4; ++i) {
            int hoff = (q * 32 + i * 8) ^ ((r & 7) << 3);
            *reinterpret_cast<float4*>(&a_s[r * 128 + hoff]) = srcA[i];
        }
    }

    // --- phase 2: wave w gathers its 16 fragment-row nodes into m_s
    {
        const int cb8 = (lane & 15) * 8;
        #pragma unroll 1
        for (int i = 0; i < 16; ++i) {
            int ln   = wave * 16 + i;            // local node row
            int node = rowBase + ln;
            int beg = row_ptr[node], end = row_ptr[node + 1];

            float acc[8];
            #pragma unroll
            for (int j = 0; j < 8; ++j) acc[j] = 0.f;

            for (int e = beg; e < end; e += 4) {
                int idx = e + (lane >> 4);
                bool valid = idx < end;
                unsigned v = sorted[valid ? idx : beg];
                int s = v & 0xFFFFu, r = v >> 16;
                const f16x8 hv = *reinterpret_cast<const f16x8*>(h16_cur   + s * D + cb8);
                const f16x8 rv = *reinterpret_cast<const f16x8*>(emb_rel16 + r * D + cb8);
                float m = valid ? 1.f : 0.f;
                #pragma unroll
                for (int j = 0; j < 8; ++j)
                    acc[j] = fmaf(m, (float)hv[j] + (float)rv[j], acc[j]);
            }
            #pragma unroll
            for (int j = 0; j < 8; ++j) {
                acc[j] += __shfl_xor(acc[j], 16, 64);
                acc[j] += __shfl_xor(acc[j], 32, 64);
            }
            if (lane < 16) {
                float inv = 1.0f / fmaxf((float)(end - beg), 1.0f);
                f16x8 o;
                #pragma unroll
                for (int j = 0; j < 8; ++j) o[j] = (f16)(acc[j] * inv);
                int hoff = cb8 ^ ((ln & 7) << 3);
                *reinterpret_cast<f16x8*>(&m_s[ln * 128 + hoff]) = o;
            }
        }
    }
    __syncthreads();

    // --- phase 3: MFMA + mix epilogue
    const int arow = wave * 16 + (lane & 15);

    f16x8 afM[4], afH[4];
    #pragma unroll
    for (int ks = 0; ks < 4; ++ks) {
        int hoff = (ks * 32 + (lane >> 4) * 8) ^ ((arow & 7) << 3);
        afM[ks] = *reinterpret_cast<const f16x8*>(&m_s[arow * 128 + hoff]);
        afH[ks] = *reinterpret_cast<const f16x8*>(&a_s[arow * 128 + hoff]);
    }

    const int orow = rowBase + arow;
    const int colq = (lane >> 4) * 4;

    f32x4 mx[8];
    float ss = 0.f;

    #pragma unroll
    for (int nt = 0; nt < 8; ++nt) {
        f32x4 accP = {0.f, 0.f, 0.f, 0.f};
        f32x4 accL = {0.f, 0.f, 0.f, 0.f};
        f32x4 accG = {0.f, 0.f, 0.f, 0.f};
        #pragma unroll
        for (int ks = 0; ks < 4; ++ks) {
            const f16x8 wfN = *reinterpret_cast<const f16x8*>(wpack + ((((0 * 8 + nt) * 4 + ks) * 64 + lane) << 3));
            const f16x8 wfL = *reinterpret_cast<const f16x8*>(wpack + ((((1 * 8 + nt) * 4 + ks) * 64 + lane) << 3));
            const f16x8 wfG = *reinterpret_cast<const f16x8*>(wpack + ((((2 * 8 + nt) * 4 + ks) * 64 + lane) << 3));
            accP = __builtin_amdgcn_mfma_f32_16x16x32_f16(wfN, afM[ks], accP, 0, 0, 0);
            accL = __builtin_amdgcn_mfma_f32_16x16x32_f16(wfL, afH[ks], accL, 0, 0, 0);
            accG = __builtin_amdgcn_mfma_f32_16x16x32_f16(wfG, afH[ks], accG, 0, 0, 0);
        }
        const size_t cidx = (size_t)orow * D + nt * 16 + colq;
        f32x4 ht = *reinterpret_cast<const f32x4*>(h_tan + cidx);
        f32x4 m;
        #pragma unroll
        for (int i = 0; i < 4; ++i) {
            float o = accP[i] + accL[i];
            o = (o >= 0.f) ? o : RRELU_SLOPE * o;
            float g = 1.0f / (1.0f + expf(-accG[i]));
            m[i] = fmaf(g, o - ht[i], ht[i]);
            ss = fmaf(m[i], m[i], ss);
        }
        mx[nt] = m;
        if (!last) {
            *reinterpret_cast<f32x4*>(h_tan + cidx) = m;
            f16x4 m16 = {(f16)m[0], (f16)m[1], (f16)m[2], (f16)m[3]};
            *reinterpret_cast<f16x4*>(h16_nxt + cidx) = m16;
        }
    }

    if (last) {
        // row-norm across the 4 colq groups (lanes differing in bits 4,5)
        ss += __shfl_xor(ss, 16, 64);
        ss += __shfl_xor(ss, 32, 64);
        float n = fmaxf(sqrtf(ss), EPS_);
        float s = tanhf(SQC * n) / (SQC * n);
        #pragma unroll
        for (int nt = 0; nt < 8; ++nt) {
            const size_t cidx = (size_t)orow * D + nt * 16 + colq;
            f32x4 o = {mx[nt][0] * s, mx[nt][1] * s, mx[nt][2] * s, mx[nt][3] * s};
            *reinterpret_cast<f32x4*>(h_out + cidx) = o;
        }
    }
}

// ---------------------------------------------------------------------------
extern "C" void kernel_launch(void* const* d_in, const int* in_sizes, int n_in,
                              void* d_out, int out_size, void* d_ws, size_t ws_size,
                              hipStream_t stream) {
    const int*   src  = (const int*)d_in[0];
    const int*   dst  = (const int*)d_in[1];
    const int*   rel  = (const int*)d_in[2];
    const float* dyn  = (const float*)d_in[3];
    const float* erel = (const float*)d_in[4];
    const float* wn   = (const float*)d_in[5];
    const float* wl   = (const float*)d_in[6];
    const float* wg   = (const float*)d_in[7];
    float* h = (float*)d_out;

    const size_t ND = (size_t)N_ENT * D;
    char* p = (char*)d_ws;
    float* h_tan    = (float*)p;            p += ND * 4;
    f16*   h16a     = (f16*)p;              p += ND * 2;
    f16*   h16b     = (f16*)p;              p += ND * 2;
    f16*   emb_rel16= (f16*)p;              p += (size_t)N_REL2 * D * 2;
    f16*   wpack    = (f16*)p;              p += (size_t)3 * D * D * 2;
    unsigned* sorted= (unsigned*)p;         p += (size_t)T_STEPS * E_EDGES * 4;
    int*   hist     = (int*)p;              p += (size_t)T_STEPS * N_ENT * 4;
    int*   scanned  = (int*)p;              p += (size_t)T_STEPS * NPAD * 4;
    int*   partial  = (int*)p;              p += (size_t)T_STEPS * 64 * 4;
    int*   row_ptr  = (int*)p;              p += (size_t)T_STEPS * (N_ENT + 1) * 4;
    int*   cursor   = (int*)p;

    const int nodeBlocks = (N_ENT * 64 + 255) / 256;           // 10000
    const int edgeB      = (E_EDGES + 255) / 256;              // 782

    // CSR build (all 8 steps)
    hipMemsetAsync(hist, 0, (size_t)T_STEPS * N_ENT * sizeof(int), stream);
    hist_kernel<<<dim3(edgeB, T_STEPS), 256, 0, stream>>>(dst, hist);
    scanA_kernel<<<dim3(40, T_STEPS), 1024, 0, stream>>>(hist, scanned, partial);
    scanB_kernel<<<T_STEPS, 64, 0, stream>>>(partial);
    scanC_kernel<<<dim3(40, T_STEPS), 1024, 0, stream>>>(hist, scanned, partial, row_ptr, cursor);
    scatter_kernel<<<dim3(edgeB, T_STEPS), 256, 0, stream>>>(src, dst, rel, cursor, sorted);

    // loop-invariant precompute
    cvt_rel_kernel<<<(N_REL2 * D + 255) / 256, 256, 0, stream>>>(erel, emb_rel16);
    cvtw_kernel<<<192, 256, 0, stream>>>(wn, wl, wg, wpack);
    logmap_kernel<<<nodeBlocks, 256, 0, stream>>>(dyn, h_tan, h16a);

    f16* bufs[2] = {h16a, h16b};
    for (int t = 0; t < T_STEPS; ++t) {
        fused_step_kernel<<<N_ENT / 64, 256, 0, stream>>>(
            bufs[t & 1], bufs[(t & 1) ^ 1], h_tan, emb_rel16, wpack,
            row_ptr + t * (N_ENT + 1), sorted + (size_t)t * E_EDGES,
            h, (t == T_STEPS - 1) ? 1 : 0);
    }
}